// Round 2
// baseline (230.455 us; speedup 1.0000x reference)
//
#include <hip/hip_runtime.h>

// Depthwise 3x3 conv (diagonal-masked dense conv), fp32.
// x: (32, 256, 64, 64). One block per (n,c) plane.
// LDS holds the plane with zero halo rows (66 x 64); each thread computes a
// 4x4 output block (4 consecutive rows x float4), so the 6 needed input row
// segments are read from LDS exactly once and reused across the 3 kh taps.

#define C_CH 256
#define H_SP 64
#define W_SP 64
#define PLANE (H_SP * W_SP)      // 4096 floats
#define LROWS (H_SP + 2)         // 66 rows incl. zero halo

__global__ __launch_bounds__(256) void dwconv3x3_kernel(
    const float* __restrict__ x,
    const float* __restrict__ Wfull,
    float* __restrict__ out)
{
    __shared__ float tile[LROWS * W_SP];   // 16.5 KiB; rows 0 and 65 are zeros

    const int p = blockIdx.x;              // plane index [0, 8192)
    const int c = p & (C_CH - 1);
    const float* __restrict__ xp = x + (size_t)p * PLANE;
    float* __restrict__ op = out + (size_t)p * PLANE;

    // 9 diagonal weights (block-uniform scalar loads)
    const float* __restrict__ wp = Wfull + (size_t)c * (C_CH + 1) * 9;
    const float w00 = wp[0], w01 = wp[1], w02 = wp[2];
    const float w10 = wp[3], w11 = wp[4], w12 = wp[5];
    const float w20 = wp[6], w21 = wp[7], w22 = wp[8];

    const int t = threadIdx.x;

    float4* tv = (float4*)tile;
    // zero the two halo rows (2 x 16 float4s)
    if (t < 16)       tv[t] = make_float4(0.f, 0.f, 0.f, 0.f);
    else if (t < 32)  tv[(H_SP + 1) * 16 + (t - 16)] = make_float4(0.f, 0.f, 0.f, 0.f);

    // stage the plane, coalesced float4; data rows start at float4 offset 16
    const float4* __restrict__ xv = (const float4*)xp;
#pragma unroll
    for (int i = 0; i < 4; ++i)
        tv[16 + t + i * 256] = xv[t + i * 256];
    __syncthreads();

    const int q  = t & 15;          // column quarter (w4 = 4q)
    const int hb = (t >> 4) << 2;   // base output row: 0..60 step 4
    const int w4 = q << 2;

    // Load 6 row segments once: center float4 + left/right halo scalars.
    float4 v[6];
    float  lf[6], rt[6];
#pragma unroll
    for (int j = 0; j < 6; ++j) {
        const int row  = hb + j;            // tile row (= x row hb+j-1)
        const int base = row * W_SP;
        v[j] = tv[row * 16 + q];
        const int li = (q == 0)  ? base : (base + w4 - 1);
        const float l = tile[li];
        lf[j] = (q == 0)  ? 0.f : l;
        const int ri = (q == 15) ? base : (base + w4 + 4);
        const float r = tile[ri];
        rt[j] = (q == 15) ? 0.f : r;
    }

    // 4 output rows, each from 3 of the 6 staged rows.
#pragma unroll
    for (int r = 0; r < 4; ++r) {
        float4 acc = make_float4(0.f, 0.f, 0.f, 0.f);
#pragma unroll
        for (int kh = 0; kh < 3; ++kh) {
            const int j = r + kh;
            float k0, k1, k2;
            if (kh == 0)      { k0 = w00; k1 = w01; k2 = w02; }
            else if (kh == 1) { k0 = w10; k1 = w11; k2 = w12; }
            else              { k0 = w20; k1 = w21; k2 = w22; }
            const float4 cv = v[j];
            acc.x = fmaf(lf[j], k0, fmaf(cv.x, k1, fmaf(cv.y, k2, acc.x)));
            acc.y = fmaf(cv.x, k0, fmaf(cv.y, k1, fmaf(cv.z, k2, acc.y)));
            acc.z = fmaf(cv.y, k0, fmaf(cv.z, k1, fmaf(cv.w, k2, acc.z)));
            acc.w = fmaf(cv.z, k0, fmaf(cv.w, k1, fmaf(rt[j], k2, acc.w)));
        }
        ((float4*)op)[(hb + r) * 16 + q] = acc;
    }
}

extern "C" void kernel_launch(void* const* d_in, const int* in_sizes, int n_in,
                              void* d_out, int out_size, void* d_ws, size_t ws_size,
                              hipStream_t stream) {
    const float* x = (const float*)d_in[0];
    const float* W = (const float*)d_in[1];
    float* out = (float*)d_out;

    const int n_planes = out_size / PLANE;  // 8192
    dwconv3x3_kernel<<<n_planes, 256, 0, stream>>>(x, W, out);
}